// Round 9
// baseline (45.341 us; speedup 1.0000x reference)
//
#include <hip/hip_runtime.h>
#include <stdint.h>

// CorrelationLayer: out[b, i*41+j, y, x] = sum_c f1[b,c,y,x]*f2[b,c,y+i-20,x+j-20]
// R9: equal-work decomposition.
//  (1) conv_kernel (1024 blocks): blocks 0..511 repack fp32 -> bf16
//      f_t[b][y][q=c/8][x] into d_ws; blocks 512..1023 zero-fill the 1680
//      all-padding output planes (3-4 each) -- overlaps conv latency, and
//      removes them from main's residency slots.
//  (2) corr_main (1024 blocks): flat enumeration of the 8816 VALID planes
//      (b,y,di); each block gets exactly 8 or 9 consecutive tasks (was 0-11
//      -> +28% makespan tail). Scalar prefix-walk start decode; increment
//      walk with bfrag reload on y change (<=1 per block). Contiguous task
//      ranges + chunked XCD swizzle keep y-band L2 locality.
// Fallback single-kernel path if ws_size < 8MB.

#define NB 4
#define NC 128
#define NH 64
#define NW 64
#define PAD 20
#define ND 41
#define HW (NH * NW)
#define ROW_U4 1024       // 16 q-groups * 64 x per (b,y) row, in uint4 units
#define VALID_TOTAL 8816  // sum over (b,y) of valid di count
#define VALID_PER_B 2204
#define ZERO_TOTAL 1680
#define ZERO_PER_B 420

typedef __attribute__((ext_vector_type(8))) __bf16 bf16x8;
typedef __attribute__((ext_vector_type(16))) float f32x16;

__device__ __forceinline__ int cntv(int y) {  // valid di count at y
  return (y < 20) ? (21 + y) : ((y < 44) ? 41 : (84 - y));
}
__device__ __forceinline__ int va0(int y) { return (y < 20) ? (20 - y) : 0; }
__device__ __forceinline__ int va1(int y) { return (y < 44) ? 41 : (84 - y); }

__device__ __forceinline__ unsigned int pk2(float a, float b) {
  // folds to v_cvt_pk_bf16_f32 (RNE)
  unsigned short lo = __builtin_bit_cast(unsigned short, (__bf16)a);
  unsigned short hi = __builtin_bit_cast(unsigned short, (__bf16)b);
  return (unsigned int)lo | ((unsigned int)hi << 16);
}

__device__ __forceinline__ float f4elem(const float4 v, int j) {
  return j == 0 ? v.x : j == 1 ? v.y : j == 2 ? v.z : v.w;
}

// ---------------- kernel 1: repack + zero-fill ----------------------------
__global__ __launch_bounds__(256) void conv_kernel(
    const float* __restrict__ f1, const float* __restrict__ f2,
    uint4* __restrict__ ws, float* __restrict__ out) {
  const int blk = blockIdx.x;  // 0..1023
  if (blk < 512) {
    // fp32 -> bf16 repack: f_t[((b*64+y)*16 + q)*64 + x] (uint4)
    const int isF2 = blk >> 8;
    const int by = blk & 255;
    const int b = by >> 6, y = by & 63;
    const float* src = (isF2 ? f2 : f1) + (size_t)b * NC * HW + (size_t)y * NW;
    uint4* dst = ws + (size_t)isF2 * (NB * NH * ROW_U4) + (size_t)by * ROW_U4;
    const int xq = threadIdx.x & 15;  // x = 4xq..4xq+3
    const int cg = threadIdx.x >> 4;  // channels 8cg..8cg+7
    const float* p = src + (size_t)cg * 8 * HW + xq * 4;
    float4 v[8];
#pragma unroll
    for (int i = 0; i < 8; ++i) v[i] = *(const float4*)(p + (size_t)i * HW);
#pragma unroll
    for (int j = 0; j < 4; ++j) {
      uint4 u;
      u.x = pk2(f4elem(v[0], j), f4elem(v[1], j));
      u.y = pk2(f4elem(v[2], j), f4elem(v[3], j));
      u.z = pk2(f4elem(v[4], j), f4elem(v[5], j));
      u.w = pk2(f4elem(v[6], j), f4elem(v[7], j));
      dst[cg * 64 + xq * 4 + j] = u;
    }
  } else {
    // zero-fill all-padding planes (yp out of range)
    const int z = blk - 512;                  // 0..511
    const int z0 = z * 3 + (z < 144 ? z : 144);
    const int nz = 3 + (z < 144 ? 1 : 0);
    const int xg = threadIdx.x & 63;
    const int g = threadIdx.x >> 6;
    for (int i = 0; i < nz; ++i) {
      const int idx = z0 + i;  // < 1680
      const int b = idx / ZERO_PER_B;
      int rz = idx - b * ZERO_PER_B;
      int y = 0;
      for (;;) {  // walk zero counts: y<20: 20-y ; 44<=y: y-43 ; else 0
        const int zc = (y < 20) ? (20 - y) : ((y >= 44) ? (y - 43) : 0);
        if (rz < zc) break;
        rz -= zc;
        ++y;
      }
      const int di = (y < 20) ? rz : (84 - y + rz);
      const size_t dB =
          (size_t)b * (ND * ND) * HW + (size_t)di * ND * HW + (size_t)y * NW;
      for (int k = g; k < ND; k += 4)
        __builtin_nontemporal_store(0.f, &out[dB + (size_t)k * HW + xg]);
    }
  }
}

// ---------------- kernel 2: banded MFMA correlation, balanced -------------
__global__ __launch_bounds__(256, 4) void corr_main(
    const uint4* __restrict__ ws, float* __restrict__ out) {
  __shared__ float cbuf[2][64 * 64];  // 32 KB -> 4 blocks/CU

  // chunked XCD swizzle: 1024 blocks; XCD c gets contiguous task band
  const int bid = blockIdx.x;
  const int h = (bid & 7) * 128 + (bid >> 3);

  // equal share of the valid-plane list: 8 or 9 tasks
  const int v0 = h * 8 + (h < 624 ? h : 624);
  const int nTask = 8 + (h < 624 ? 1 : 0);

  int b = v0 / VALID_PER_B;
  int r = v0 - b * VALID_PER_B;
  int y = 0;
  for (;;) {  // prefix walk: find y with Q(y) <= r < Q(y)+cnt(y)
    const int c = cntv(y);
    if (r < c) break;
    r -= c;
    ++y;
  }
  int di = va0(y) + r;

  const int t = threadIdx.x;
  const int lane = t & 63;
  const int wv = t >> 6;  // wave -> 32x32 C tile (I=row half, J=col half)
  const int I = wv & 1;
  const int J = wv >> 1;
  const int kh = lane >> 5;

  // mfma_f32_32x32x16_bf16: A row = lane&31 (+32I), B col = lane&31 (+32J),
  // frag ks -> q = 2ks+kh. C/D: col = lane&31 (+32J),
  // row = 32I + 4kh + (r&3) + 8*(r>>2).   (verified: absmax 0.5 passes)
  const int xa = I * 32 + (lane & 31);
  const int xb = J * 32 + (lane & 31);
  const int col = (lane & 31) + 32 * J;
  const int rbase = kh * 4 + I * 32;
  const int xg = t & 63;  // extract/store mapping
  const int g = t >> 6;

  const uint4* f1t = ws;
  const uint4* f2t = ws + NB * NH * ROW_U4;

  // per-(b,y) state
  const uint4* f1row = f1t + (size_t)(b * 64 + y) * ROW_U4 + kh * 64 + xb;
  const uint4* f2row = f2t + (size_t)(b * 64) * ROW_U4 + kh * 64 + xa;
  size_t outBase = (size_t)b * (ND * ND) * HW + (size_t)y * NW;
  bf16x8 bfrag[8];
#pragma unroll
  for (int ks = 0; ks < 8; ++ks)
    bfrag[ks] = __builtin_bit_cast(bf16x8, f1row[ks * 128]);

  int p = 0;
  size_t prevDB = 0;
#pragma unroll 1
  for (int j = 0; j < nTask; ++j) {
    const int yp = y + di - PAD;  // valid by construction
    const uint4* ap = f2row + (size_t)yp * ROW_U4;
    uint4 a[8];  // A fragments, issued first
#pragma unroll
    for (int ks = 0; ks < 8; ++ks) a[ks] = ap[ks * 128];

    if (j > 0) {  // lag-extract previous plane while A loads in flight
      const float* cb = cbuf[p ^ 1];
      for (int k = g; k < ND; k += 4) {
        const int xs = xg + k - PAD;
        const float vv = (xs >= 0 && xs < NW) ? cb[xs * 64 + xg] : 0.f;
        __builtin_nontemporal_store(vv, &out[prevDB + (size_t)k * HW + xg]);
      }
    }

    f32x16 acc;
#pragma unroll
    for (int q = 0; q < 16; ++q) acc[q] = 0.f;
#pragma unroll
    for (int ks = 0; ks < 8; ++ks)
      acc = __builtin_amdgcn_mfma_f32_32x32x16_bf16(
          __builtin_bit_cast(bf16x8, a[ks]), bfrag[ks], acc, 0, 0, 0);
#pragma unroll
    for (int q = 0; q < 16; ++q) {
      const int row = rbase + (q & 3) + 8 * (q >> 2);
      cbuf[p][row * 64 + col] = acc[q];  // banks col%32: 2-way = free
    }
    __syncthreads();  // cbuf[p] visible; p^1 extract reads drained

    prevDB = outBase + (size_t)di * ND * HW;
    // advance to next valid plane (guarded: no state reload past the end)
    ++di;
    if (di == va1(y) && j + 1 < nTask) {
      ++y;
      if (y == 64) {
        y = 0;
        ++b;
      }
      di = va0(y);
      f1row = f1t + (size_t)(b * 64 + y) * ROW_U4 + kh * 64 + xb;
      f2row = f2t + (size_t)(b * 64) * ROW_U4 + kh * 64 + xa;
      outBase = (size_t)b * (ND * ND) * HW + (size_t)y * NW;
#pragma unroll
      for (int ks = 0; ks < 8; ++ks)
        bfrag[ks] = __builtin_bit_cast(bf16x8, f1row[ks * 128]);
    }
    p ^= 1;
  }

  {  // epilogue extract of the last plane
    const float* cb = cbuf[p ^ 1];
    for (int k = g; k < ND; k += 4) {
      const int xs = xg + k - PAD;
      const float vv = (xs >= 0 && xs < NW) ? cb[xs * 64 + xg] : 0.f;
      __builtin_nontemporal_store(vv, &out[prevDB + (size_t)k * HW + xg]);
    }
  }
}

// ---------------- fallback (single-kernel path, no ws) --------------------
__device__ __forceinline__ void convwrite(const float4 (&v)[8],
                                          uint4* __restrict__ lds, int xq,
                                          int cg) {
#pragma unroll
  for (int j = 0; j < 4; ++j) {
    const int x = xq * 4 + j;
    uint4 u;
    u.x = pk2(f4elem(v[0], j), f4elem(v[1], j));
    u.y = pk2(f4elem(v[2], j), f4elem(v[3], j));
    u.z = pk2(f4elem(v[4], j), f4elem(v[5], j));
    u.w = pk2(f4elem(v[6], j), f4elem(v[7], j));
    lds[x * 16 + (cg ^ (x & 7))] = u;
  }
}

__global__ __launch_bounds__(256, 2) void corr_fallback(
    const float* __restrict__ feat1, const float* __restrict__ feat2,
    float* __restrict__ out) {
  __shared__ uint4 f2s[2][64 * 16];
  __shared__ float cbuf[2][64 * 64];

  const int bid = blockIdx.x;
  const int lid = (bid & 7) * 64 + (bid >> 3);
  const int half = lid & 1;
  const int y = (lid >> 1) & 63;
  const int b = lid >> 7;

  const int t = threadIdx.x;
  const int lane = t & 63;
  const int wv = t >> 6;
  const int I = wv & 1;
  const int J = wv >> 1;
  const int xa = I * 32 + (lane & 31);
  const int xb = J * 32 + (lane & 31);
  const int kh = lane >> 5;
  const int aBase = xa * 16, aSw = xa & 7;
  const int bBase = xb * 16, bSw = xb & 7;
  const int col = (lane & 31) + J * 32;
  const int rbase = kh * 4 + I * 32;
  const int xg = t & 63;
  const int g = t >> 6;
  const int xq = t & 15;
  const int cg = t >> 4;
  const size_t rowoff = (size_t)cg * 8 * HW + xq * 4;
  const float* f1row = feat1 + (size_t)b * NC * HW + (size_t)y * NW + rowoff;
  const float* f2row0 = feat2 + (size_t)b * NC * HW + rowoff;
  const size_t outBase = ((size_t)b * (ND * ND) * NH + y) * NW;

  int dBeg, dEnd;
  if (half == 0) {
    dBeg = (y < PAD) ? (PAD - y) : 0;
    dEnd = PAD + 1;
  } else {
    dBeg = PAD + 1;
    const int e = (NH + PAD) - y;
    dEnd = e < ND ? e : ND;
  }
  const int zBeg = half ? dEnd : 0;
  const int zEnd = half ? ND : dBeg;
  for (int di = zBeg; di < zEnd; ++di) {
    const size_t dB = outBase + (size_t)di * ND * HW;
    for (int k = g; k < ND; k += 4) out[dB + (size_t)k * HW + xg] = 0.f;
  }
  if (dBeg >= dEnd) return;

  float4 v[8];
#pragma unroll
  for (int i = 0; i < 8; ++i) v[i] = *(const float4*)(f1row + (size_t)i * HW);
  uint4* f1tmp = (uint4*)&cbuf[0][0];
  convwrite(v, f1tmp, xq, cg);
  {
    const int yp0 = y + dBeg - PAD;
#pragma unroll
    for (int i = 0; i < 8; ++i)
      v[i] = *(const float4*)(f2row0 + (size_t)yp0 * NW + (size_t)i * HW);
  }
  __syncthreads();
  bf16x8 bfrag[8];
#pragma unroll
  for (int ks = 0; ks < 8; ++ks) {
    const int q = ks * 2 + kh;
    bfrag[ks] = __builtin_bit_cast(bf16x8, f1tmp[bBase + (q ^ bSw)]);
  }
  __syncthreads();

  const int nIter = dEnd - dBeg;
  int p = 0;
#pragma unroll 1
  for (int j = 0; j < nIter; ++j) {
    convwrite(v, f2s[p], xq, cg);
    {
      const int nj = (j + 1 < nIter) ? j + 1 : j;
      const int ypn = y + dBeg + nj - PAD;
#pragma unroll
      for (int i = 0; i < 8; ++i)
        v[i] = *(const float4*)(f2row0 + (size_t)ypn * NW + (size_t)i * HW);
    }
    __syncthreads();

    f32x16 acc;
#pragma unroll
    for (int q = 0; q < 16; ++q) acc[q] = 0.f;
#pragma unroll
    for (int ks = 0; ks < 8; ++ks) {
      const int q = ks * 2 + kh;
      bf16x8 aa = __builtin_bit_cast(bf16x8, f2s[p][aBase + (q ^ aSw)]);
      acc = __builtin_amdgcn_mfma_f32_32x32x16_bf16(aa, bfrag[ks], acc, 0, 0, 0);
    }
#pragma unroll
    for (int q = 0; q < 16; ++q) {
      const int row = rbase + (q & 3) + 8 * (q >> 2);
      cbuf[p][row * 64 + col] = acc[q];
    }
    if (j > 0) {
      const size_t dBase = outBase + (size_t)(dBeg + j - 1) * ND * HW;
      const float* cb = cbuf[p ^ 1];
      for (int k = g; k < ND; k += 4) {
        const int xs = xg + k - PAD;
        const float vv = (xs >= 0 && xs < NW) ? cb[xs * 64 + xg] : 0.f;
        out[dBase + (size_t)k * HW + xg] = vv;
      }
    }
    p ^= 1;
  }
  __syncthreads();
  {
    const size_t dBase = outBase + (size_t)(dEnd - 1) * ND * HW;
    const float* cb = cbuf[p ^ 1];
    for (int k = g; k < ND; k += 4) {
      const int xs = xg + k - PAD;
      const float vv = (xs >= 0 && xs < NW) ? cb[xs * 64 + xg] : 0.f;
      out[dBase + (size_t)k * HW + xg] = vv;
    }
  }
}

extern "C" void kernel_launch(void* const* d_in, const int* in_sizes, int n_in,
                              void* d_out, int out_size, void* d_ws,
                              size_t ws_size, hipStream_t stream) {
  (void)in_sizes; (void)n_in; (void)out_size;
  const float* f1 = (const float*)d_in[0];
  const float* f2 = (const float*)d_in[1];
  float* out = (float*)d_out;
  const size_t need = (size_t)2 * NB * NH * ROW_U4 * sizeof(uint4);  // 8 MB
  if (ws_size >= need && d_ws != nullptr) {
    uint4* ws = (uint4*)d_ws;
    conv_kernel<<<dim3(1024), dim3(256), 0, stream>>>(f1, f2, ws, out);
    corr_main<<<dim3(1024), dim3(256), 0, stream>>>(ws, out);
  } else {
    corr_fallback<<<dim3(NB * NH * 2), dim3(256), 0, stream>>>(f1, f2, out);
  }
}

// Round 10
// 42.486 us; speedup vs baseline: 1.0672x; 1.0672x over previous
//
#include <hip/hip_runtime.h>
#include <stdint.h>

// CorrelationLayer: out[b, i*41+j, y, x] = sum_c f1[b,c,y,x]*f2[b,c,y+i-20,x+j-20]
// R10: plane-contiguous writer WITHOUT R7's regressions.
//  (1) conv_kernel (512 blocks): fp32 -> bf16 repack f_t[b][y][q=c/8][x].
//  (2) corr_main (2624 blocks = b,di,y-tile4, 3 blocks/CU): per y, MFMA the
//      64x64 C tile and scatter the banded elements STRAIGHT from acc regs
//      into diag[k][yy][x] (k = xs-xg+20; out-of-band -> dump slot via
//      cndmask). Waves write disjoint diag entries -> NO barriers in the
//      4-y loop; 2 barriers per block total (post-memset, pre-flush).
//      Pre-zeroed diag makes all padding (y-planes and x-edges) uniform --
//      all-invalid blocks are pure zero-fill flushes, no special casing.
//      Flush: each k-plane = one 1KB-contiguous dwordx4 nt-store; the 16
//      same-(b,di) blocks co-resident per XCD cover full 16KB planes.
// Fallback single-kernel path if ws_size < 8MB.

#define NB 4
#define NC 128
#define NH 64
#define NW 64
#define PAD 20
#define ND 41
#define HW (NH * NW)
#define ROW_U4 1024      // 16 q-groups * 64 x per (b,y) row, in uint4 units
#define DIAG_N (ND * 256)  // diag floats: [k][yy][x] = 41*4*64

typedef __attribute__((ext_vector_type(8))) __bf16 bf16x8;
typedef __attribute__((ext_vector_type(16))) float f32x16;
typedef __attribute__((ext_vector_type(4))) float f32x4;

__device__ __forceinline__ unsigned int pk2(float a, float b) {
  // folds to v_cvt_pk_bf16_f32 (RNE)
  unsigned short lo = __builtin_bit_cast(unsigned short, (__bf16)a);
  unsigned short hi = __builtin_bit_cast(unsigned short, (__bf16)b);
  return (unsigned int)lo | ((unsigned int)hi << 16);
}

__device__ __forceinline__ float f4elem(const float4 v, int j) {
  return j == 0 ? v.x : j == 1 ? v.y : j == 2 ? v.z : v.w;
}

// ---------------- kernel 1: fp32 -> bf16 repack --------------------------
// f_t[((b*64+y)*16 + q)*64 + x] (uint4) = channels 8q..8q+7 at (y,x), bf16.
__global__ __launch_bounds__(256) void conv_kernel(
    const float* __restrict__ f1, const float* __restrict__ f2,
    uint4* __restrict__ ws) {
  const int blk = blockIdx.x;  // 0..511
  const int isF2 = blk >> 8;
  const int by = blk & 255;  // b*64+y
  const int b = by >> 6, y = by & 63;
  const float* src = (isF2 ? f2 : f1) + (size_t)b * NC * HW + (size_t)y * NW;
  uint4* dst = ws + (size_t)isF2 * (NB * NH * ROW_U4) + (size_t)by * ROW_U4;
  const int xq = threadIdx.x & 15;  // x = 4xq..4xq+3 (float4)
  const int cg = threadIdx.x >> 4;  // channels 8cg..8cg+7
  const float* p = src + (size_t)cg * 8 * HW + xq * 4;
  float4 v[8];
#pragma unroll
  for (int i = 0; i < 8; ++i) v[i] = *(const float4*)(p + (size_t)i * HW);
#pragma unroll
  for (int j = 0; j < 4; ++j) {
    uint4 u;
    u.x = pk2(f4elem(v[0], j), f4elem(v[1], j));
    u.y = pk2(f4elem(v[2], j), f4elem(v[3], j));
    u.z = pk2(f4elem(v[4], j), f4elem(v[5], j));
    u.w = pk2(f4elem(v[6], j), f4elem(v[7], j));
    dst[cg * 64 + xq * 4 + j] = u;
  }
}

// ---------------- kernel 2: banded MFMA, plane-contiguous writer ----------
__global__ __launch_bounds__(256, 3) void corr_main(
    const uint4* __restrict__ ws, float* __restrict__ out) {
  __shared__ float diag[DIAG_N + 64];  // 42.25 KB -> 3 blocks/CU

  // XCD-chunk swizzle: 2624 = 8*328 bijective. Per XCD: 328 lids = 16 y-tiles
  // x ~21 consecutive (b,di) -> f1t/f2t slice ~2MB L2-resident; the 16
  // same-(b,di) blocks cover each full 16KB output plane.
  const int raw = blockIdx.x;
  const int lid = (raw & 7) * 328 + (raw >> 3);
  const int y4 = lid & 15;
  const int rest = lid >> 4;  // 0..163 = b*41+di
  const int di = rest % ND;
  const int b = rest / ND;
  const int y0 = y4 * 4;

  const int t = threadIdx.x;
  const int lane = t & 63;
  const int wv = t >> 6;  // wave -> 32x32 C quadrant (I=row half, J=col half)
  const int I = wv & 1;
  const int J = wv >> 1;
  const int kh = lane >> 5;

  // mfma_f32_32x32x16_bf16: A row = lane&31 (+32I), B col = lane&31 (+32J),
  // frag ks -> q = 2ks+kh. C/D: col = lane&31 (+32J),
  // row(q) = 32I + 4kh + (q&3) + 8*(q>>2).   (verified: absmax 0.5)
  const int xa = I * 32 + (lane & 31);   // x' row
  const int col = J * 32 + (lane & 31);  // x col
  const int rbase = kh * 4 + I * 32;
  const int kbase = rbase - col + PAD;  // k of acc element q=0

  // pre-zero diag (+dump): padding becomes uniform, no special cases
  for (int i = t; i < DIAG_N + 64; i += 256) diag[i] = 0.f;
  __syncthreads();

  const uint4* f1t = ws;
  const uint4* f2t = ws + NB * NH * ROW_U4;

#pragma unroll 2
  for (int yy = 0; yy < 4; ++yy) {
    const int y = y0 + yy;
    const int yp = y + di - PAD;
    if (yp >= 0 && yp < NH) {  // block-uniform
      const uint4* ap = f2t + (size_t)(b * 64 + yp) * ROW_U4 + kh * 64 + xa;
      const uint4* bp = f1t + (size_t)(b * 64 + y) * ROW_U4 + kh * 64 + col;
      uint4 a[8], bb[8];
#pragma unroll
      for (int ks = 0; ks < 8; ++ks) {
        a[ks] = ap[ks * 128];
        bb[ks] = bp[ks * 128];
      }
      f32x16 acc;
#pragma unroll
      for (int q = 0; q < 16; ++q) acc[q] = 0.f;
#pragma unroll
      for (int ks = 0; ks < 8; ++ks)
        acc = __builtin_amdgcn_mfma_f32_32x32x16_bf16(
            __builtin_bit_cast(bf16x8, a[ks]),
            __builtin_bit_cast(bf16x8, bb[ks]), acc, 0, 0, 0);

      // scatter band elements straight from acc: k = xs - col + 20.
      // waves own disjoint (k,x) sets -> no barrier needed across yy.
      const int base = yy * 64 + col;  // float index within one k-slab
#pragma unroll
      for (int q = 0; q < 16; ++q) {
        const int ke = kbase + (q & 3) + 8 * (q >> 2);
        const int idx =
            ((unsigned)ke < (unsigned)ND) ? ke * 256 + base : DIAG_N + lane;
        diag[idx] = acc[q];  // bank = col%32 (2-way = free); dump merged
      }
    }
  }
  __syncthreads();  // diag complete

  // flush: one 1KB-contiguous dwordx4 nt-store per k-plane
  const int g = t >> 6;
  const size_t outRow = ((size_t)(b * (ND * ND) + di * ND) * NH + y0) * NW;
  for (int k = g; k < ND; k += 4) {
    const f32x4 v = *(const f32x4*)&diag[k * 256 + lane * 4];
    __builtin_nontemporal_store(
        v, (f32x4*)(out + outRow + (size_t)k * HW + lane * 4));
  }
}

// ---------------- fallback (single-kernel path, no ws) --------------------
__device__ __forceinline__ void convwrite(const float4 (&v)[8],
                                          uint4* __restrict__ lds, int xq,
                                          int cg) {
#pragma unroll
  for (int j = 0; j < 4; ++j) {
    const int x = xq * 4 + j;
    uint4 u;
    u.x = pk2(f4elem(v[0], j), f4elem(v[1], j));
    u.y = pk2(f4elem(v[2], j), f4elem(v[3], j));
    u.z = pk2(f4elem(v[4], j), f4elem(v[5], j));
    u.w = pk2(f4elem(v[6], j), f4elem(v[7], j));
    lds[x * 16 + (cg ^ (x & 7))] = u;
  }
}

__global__ __launch_bounds__(256, 2) void corr_fallback(
    const float* __restrict__ feat1, const float* __restrict__ feat2,
    float* __restrict__ out) {
  __shared__ uint4 f2s[2][64 * 16];
  __shared__ float cbuf[2][64 * 64];

  const int bid = blockIdx.x;
  const int lid = (bid & 7) * 64 + (bid >> 3);
  const int half = lid & 1;
  const int y = (lid >> 1) & 63;
  const int b = lid >> 7;

  const int t = threadIdx.x;
  const int lane = t & 63;
  const int wv = t >> 6;
  const int I = wv & 1;
  const int J = wv >> 1;
  const int xa = I * 32 + (lane & 31);
  const int xb = J * 32 + (lane & 31);
  const int kh = lane >> 5;
  const int aBase = xa * 16, aSw = xa & 7;
  const int bBase = xb * 16, bSw = xb & 7;
  const int col = (lane & 31) + J * 32;
  const int rbase = kh * 4 + I * 32;
  const int xg = t & 63;
  const int g = t >> 6;
  const int xq = t & 15;
  const int cg = t >> 4;
  const size_t rowoff = (size_t)cg * 8 * HW + xq * 4;
  const float* f1row = feat1 + (size_t)b * NC * HW + (size_t)y * NW + rowoff;
  const float* f2row0 = feat2 + (size_t)b * NC * HW + rowoff;
  const size_t outBase = ((size_t)b * (ND * ND) * NH + y) * NW;

  int dBeg, dEnd;
  if (half == 0) {
    dBeg = (y < PAD) ? (PAD - y) : 0;
    dEnd = PAD + 1;
  } else {
    dBeg = PAD + 1;
    const int e = (NH + PAD) - y;
    dEnd = e < ND ? e : ND;
  }
  const int zBeg = half ? dEnd : 0;
  const int zEnd = half ? ND : dBeg;
  for (int di = zBeg; di < zEnd; ++di) {
    const size_t dB = outBase + (size_t)di * ND * HW;
    for (int k = g; k < ND; k += 4) out[dB + (size_t)k * HW + xg] = 0.f;
  }
  if (dBeg >= dEnd) return;

  float4 v[8];
#pragma unroll
  for (int i = 0; i < 8; ++i) v[i] = *(const float4*)(f1row + (size_t)i * HW);
  uint4* f1tmp = (uint4*)&cbuf[0][0];
  convwrite(v, f1tmp, xq, cg);
  {
    const int yp0 = y + dBeg - PAD;
#pragma unroll
    for (int i = 0; i < 8; ++i)
      v[i] = *(const float4*)(f2row0 + (size_t)yp0 * NW + (size_t)i * HW);
  }
  __syncthreads();
  bf16x8 bfrag[8];
#pragma unroll
  for (int ks = 0; ks < 8; ++ks) {
    const int q = ks * 2 + kh;
    bfrag[ks] = __builtin_bit_cast(bf16x8, f1tmp[bBase + (q ^ bSw)]);
  }
  __syncthreads();

  const int nIter = dEnd - dBeg;
  int p = 0;
#pragma unroll 1
  for (int j = 0; j < nIter; ++j) {
    convwrite(v, f2s[p], xq, cg);
    {
      const int nj = (j + 1 < nIter) ? j + 1 : j;
      const int ypn = y + dBeg + nj - PAD;
#pragma unroll
      for (int i = 0; i < 8; ++i)
        v[i] = *(const float4*)(f2row0 + (size_t)ypn * NW + (size_t)i * HW);
    }
    __syncthreads();

    f32x16 acc;
#pragma unroll
    for (int q = 0; q < 16; ++q) acc[q] = 0.f;
#pragma unroll
    for (int ks = 0; ks < 8; ++ks) {
      const int q = ks * 2 + kh;
      bf16x8 aa = __builtin_bit_cast(bf16x8, f2s[p][aBase + (q ^ aSw)]);
      acc = __builtin_amdgcn_mfma_f32_32x32x16_bf16(aa, bfrag[ks], acc, 0, 0, 0);
    }
#pragma unroll
    for (int q = 0; q < 16; ++q) {
      const int row = rbase + (q & 3) + 8 * (q >> 2);
      cbuf[p][row * 64 + col] = acc[q];
    }
    if (j > 0) {
      const size_t dBase = outBase + (size_t)(dBeg + j - 1) * ND * HW;
      const float* cb = cbuf[p ^ 1];
      for (int k = g; k < ND; k += 4) {
        const int xs = xg + k - PAD;
        const float vv = (xs >= 0 && xs < NW) ? cb[xs * 64 + xg] : 0.f;
        out[dBase + (size_t)k * HW + xg] = vv;
      }
    }
    p ^= 1;
  }
  __syncthreads();
  {
    const size_t dBase = outBase + (size_t)(dEnd - 1) * ND * HW;
    const float* cb = cbuf[p ^ 1];
    for (int k = g; k < ND; k += 4) {
      const int xs = xg + k - PAD;
      const float vv = (xs >= 0 && xs < NW) ? cb[xs * 64 + xg] : 0.f;
      out[dBase + (size_t)k * HW + xg] = vv;
    }
  }
}

extern "C" void kernel_launch(void* const* d_in, const int* in_sizes, int n_in,
                              void* d_out, int out_size, void* d_ws,
                              size_t ws_size, hipStream_t stream) {
  (void)in_sizes; (void)n_in; (void)out_size;
  const float* f1 = (const float*)d_in[0];
  const float* f2 = (const float*)d_in[1];
  float* out = (float*)d_out;
  const size_t need = (size_t)2 * NB * NH * ROW_U4 * sizeof(uint4);  // 8 MB
  if (ws_size >= need && d_ws != nullptr) {
    uint4* ws = (uint4*)d_ws;
    conv_kernel<<<dim3(512), dim3(256), 0, stream>>>(f1, f2, ws);
    corr_main<<<dim3(NB * ND * 16), dim3(256), 0, stream>>>(ws, out);
  } else {
    corr_fallback<<<dim3(NB * NH * 2), dim3(256), 0, stream>>>(f1, f2, out);
  }
}